// Round 1
// baseline (1128.288 us; speedup 1.0000x reference)
//
#include <hip/hip_runtime.h>

// MultiClassDiceLoss: labels {1,2,3}, vols are float32 with values in {0,1,2,3}.
// dice_l = 2*|A_l & B_l| / (|A_l| + |B_l| + eps); out = 1 - mean(dice_l).
// Memory-bound: 2 x 512^3 x 4B = 1.07 GB read, one pass.

#define NCNT 9   // c1[1..3], c2[1..3], inter[1..3]

__global__ void dice_zero_ws(unsigned int* counters) {
    int i = threadIdx.x;
    if (i < NCNT) counters[i] = 0u;
}

__global__ __launch_bounds__(256) void dice_count(const float4* __restrict__ a,
                                                  const float4* __restrict__ b,
                                                  unsigned int* __restrict__ counters,
                                                  int n4) {
    unsigned int c[NCNT];
#pragma unroll
    for (int k = 0; k < NCNT; ++k) c[k] = 0u;

    const int stride = gridDim.x * blockDim.x;
    for (int i = blockIdx.x * blockDim.x + threadIdx.x; i < n4; i += stride) {
        float4 x = a[i];
        float4 y = b[i];
#pragma unroll
        for (int comp = 0; comp < 4; ++comp) {
            float xa = (comp == 0) ? x.x : (comp == 1) ? x.y : (comp == 2) ? x.z : x.w;
            float yb = (comp == 0) ? y.x : (comp == 1) ? y.y : (comp == 2) ? y.z : y.w;
            bool a1 = (xa == 1.0f), a2 = (xa == 2.0f), a3 = (xa == 3.0f);
            bool b1 = (yb == 1.0f), b2 = (yb == 2.0f), b3 = (yb == 3.0f);
            c[0] += a1; c[1] += a2; c[2] += a3;
            c[3] += b1; c[4] += b2; c[5] += b3;
            c[6] += a1 & b1; c[7] += a2 & b2; c[8] += a3 & b3;
        }
    }

    // wave-level reduction (wave = 64 lanes)
#pragma unroll
    for (int k = 0; k < NCNT; ++k) {
#pragma unroll
        for (int off = 32; off > 0; off >>= 1)
            c[k] += __shfl_down(c[k], off, 64);
    }

    __shared__ unsigned int s[4][NCNT];  // 256 threads -> 4 waves
    const int wave = threadIdx.x >> 6;
    const int lane = threadIdx.x & 63;
    if (lane == 0) {
#pragma unroll
        for (int k = 0; k < NCNT; ++k) s[wave][k] = c[k];
    }
    __syncthreads();
    if (threadIdx.x == 0) {
#pragma unroll
        for (int k = 0; k < NCNT; ++k) {
            unsigned int v = s[0][k] + s[1][k] + s[2][k] + s[3][k];
            atomicAdd(&counters[k], v);
        }
    }
}

__global__ void dice_finalize(const unsigned int* __restrict__ counters,
                              float* __restrict__ out) {
    // eps = np.finfo(np.float32).eps
    const double eps = 1.1920928955078125e-07;
    double acc = 0.0;
#pragma unroll
    for (int l = 0; l < 3; ++l) {
        double c1 = (double)counters[l];
        double c2 = (double)counters[3 + l];
        double in = (double)counters[6 + l];
        acc += (2.0 * in) / (c1 + c2 + eps);
    }
    out[0] = (float)(1.0 - acc / 3.0);
}

extern "C" void kernel_launch(void* const* d_in, const int* in_sizes, int n_in,
                              void* d_out, int out_size, void* d_ws, size_t ws_size,
                              hipStream_t stream) {
    const float* v1 = (const float*)d_in[0];
    const float* v2 = (const float*)d_in[1];
    float* out = (float*)d_out;
    unsigned int* counters = (unsigned int*)d_ws;

    const int n = in_sizes[0];        // 512^3 = 134217728, divisible by 4
    const int n4 = n >> 2;

    dice_zero_ws<<<1, 64, 0, stream>>>(counters);

    const int threads = 256;
    const int blocks = 2048;          // 8 blocks/CU, 64 float4-iters/thread
    dice_count<<<blocks, threads, 0, stream>>>(
        (const float4*)v1, (const float4*)v2, counters, n4);

    dice_finalize<<<1, 1, 0, stream>>>(counters, out);
}

// Round 2
// 1122.928 us; speedup vs baseline: 1.0048x; 1.0048x over previous
//
#include <hip/hip_runtime.h>

// MultiClassDiceLoss: labels {1,2,3}, vols are float32 with values in {0,1,2,3}.
// dice_l = 2*|A_l & B_l| / (|A_l| + |B_l| + eps); out = 1 - mean(dice_l).
// Memory-bound one-pass reduction over 2 x 512^3 x 4B = 1.07 GB.
// R1 lesson: 2 outstanding loads/wave -> latency-bound at 16% HBM. Fix: U=4
// unroll -> 8 independent dwordx4 loads in flight per thread.

#define NCNT 9   // c1[1..3], c2[1..3], inter[1..3]
#define UNROLL 4

__global__ void dice_zero_ws(unsigned int* counters) {
    int i = threadIdx.x;
    if (i < NCNT) counters[i] = 0u;
}

__device__ __forceinline__ void count4(float4 x, float4 y, unsigned int* c) {
#pragma unroll
    for (int comp = 0; comp < 4; ++comp) {
        float xa = (comp == 0) ? x.x : (comp == 1) ? x.y : (comp == 2) ? x.z : x.w;
        float yb = (comp == 0) ? y.x : (comp == 1) ? y.y : (comp == 2) ? y.z : y.w;
        bool a1 = (xa == 1.0f), a2 = (xa == 2.0f), a3 = (xa == 3.0f);
        bool b1 = (yb == 1.0f), b2 = (yb == 2.0f), b3 = (yb == 3.0f);
        c[0] += a1; c[1] += a2; c[2] += a3;
        c[3] += b1; c[4] += b2; c[5] += b3;
        c[6] += a1 & b1; c[7] += a2 & b2; c[8] += a3 & b3;
    }
}

__global__ __launch_bounds__(256) void dice_count(const float4* __restrict__ a,
                                                  const float4* __restrict__ b,
                                                  unsigned int* __restrict__ counters,
                                                  int n4) {
    unsigned int c[NCNT];
#pragma unroll
    for (int k = 0; k < NCNT; ++k) c[k] = 0u;

    const int nthreads = gridDim.x * blockDim.x;
    const int tid = blockIdx.x * blockDim.x + threadIdx.x;
    const int big_stride = nthreads * UNROLL;

    int i = tid;
    // main unrolled loop: 8 independent 16B loads in flight
    for (; i + (UNROLL - 1) * nthreads < n4; i += big_stride) {
        float4 x0 = a[i];
        float4 x1 = a[i + nthreads];
        float4 x2 = a[i + 2 * nthreads];
        float4 x3 = a[i + 3 * nthreads];
        float4 y0 = b[i];
        float4 y1 = b[i + nthreads];
        float4 y2 = b[i + 2 * nthreads];
        float4 y3 = b[i + 3 * nthreads];
        count4(x0, y0, c);
        count4(x1, y1, c);
        count4(x2, y2, c);
        count4(x3, y3, c);
    }
    // tail (not taken for 512^3 with 2048x256 grid, kept for safety)
    for (; i < n4; i += nthreads) {
        count4(a[i], b[i], c);
    }

    // wave-level reduction (wave = 64 lanes)
#pragma unroll
    for (int k = 0; k < NCNT; ++k) {
#pragma unroll
        for (int off = 32; off > 0; off >>= 1)
            c[k] += __shfl_down(c[k], off, 64);
    }

    __shared__ unsigned int s[4][NCNT];  // 256 threads -> 4 waves
    const int wave = threadIdx.x >> 6;
    const int lane = threadIdx.x & 63;
    if (lane == 0) {
#pragma unroll
        for (int k = 0; k < NCNT; ++k) s[wave][k] = c[k];
    }
    __syncthreads();
    if (threadIdx.x == 0) {
#pragma unroll
        for (int k = 0; k < NCNT; ++k) {
            unsigned int v = s[0][k] + s[1][k] + s[2][k] + s[3][k];
            atomicAdd(&counters[k], v);
        }
    }
}

__global__ void dice_finalize(const unsigned int* __restrict__ counters,
                              float* __restrict__ out) {
    const double eps = 1.1920928955078125e-07;  // np.float32 eps
    double acc = 0.0;
#pragma unroll
    for (int l = 0; l < 3; ++l) {
        double c1 = (double)counters[l];
        double c2 = (double)counters[3 + l];
        double in = (double)counters[6 + l];
        acc += (2.0 * in) / (c1 + c2 + eps);
    }
    out[0] = (float)(1.0 - acc / 3.0);
}

extern "C" void kernel_launch(void* const* d_in, const int* in_sizes, int n_in,
                              void* d_out, int out_size, void* d_ws, size_t ws_size,
                              hipStream_t stream) {
    const float* v1 = (const float*)d_in[0];
    const float* v2 = (const float*)d_in[1];
    float* out = (float*)d_out;
    unsigned int* counters = (unsigned int*)d_ws;

    const int n = in_sizes[0];        // 512^3 = 134217728, divisible by 4
    const int n4 = n >> 2;

    dice_zero_ws<<<1, 64, 0, stream>>>(counters);

    const int threads = 256;
    const int blocks = 2048;          // 8 blocks/CU -> 32 waves/CU (full)
    dice_count<<<blocks, threads, 0, stream>>>(
        (const float4*)v1, (const float4*)v2, counters, n4);

    dice_finalize<<<1, 1, 0, stream>>>(counters, out);
}

// Round 3
// 1046.740 us; speedup vs baseline: 1.0779x; 1.0728x over previous
//
#include <hip/hip_runtime.h>

// MultiClassDiceLoss: labels {1,2,3}, float32 vols with values in {0,1,2,3}.
// dice_l = 2*|A_l & B_l| / (|A_l| + |B_l| + eps); out = 1 - mean(dice_l).
// One-pass reduction over 2 x 512 MiB. R2 lesson: compiler interleaved
// loads+compute (VGPR=28 < 32 needed for 8 live float4) -> MLP never rose.
// R3: block-linear contiguous chunks + forced 8-deep load window
// (sched_barrier) + nontemporal loads.

#define NCNT 9   // c1[1..3], c2[1..3], inter[1..3]
#define UNROLL 4

typedef float v4f __attribute__((ext_vector_type(4)));

__global__ void dice_zero_ws(unsigned int* counters) {
    int i = threadIdx.x;
    if (i < NCNT) counters[i] = 0u;
}

__device__ __forceinline__ void count4(v4f x, v4f y, unsigned int* c) {
#pragma unroll
    for (int comp = 0; comp < 4; ++comp) {
        float xa = x[comp];
        float yb = y[comp];
        bool a1 = (xa == 1.0f), a2 = (xa == 2.0f), a3 = (xa == 3.0f);
        bool b1 = (yb == 1.0f), b2 = (yb == 2.0f), b3 = (yb == 3.0f);
        c[0] += a1; c[1] += a2; c[2] += a3;
        c[3] += b1; c[4] += b2; c[5] += b3;
        c[6] += a1 & b1; c[7] += a2 & b2; c[8] += a3 & b3;
    }
}

__global__ __launch_bounds__(256) void dice_count(const v4f* __restrict__ a,
                                                  const v4f* __restrict__ b,
                                                  unsigned int* __restrict__ counters,
                                                  int n4) {
    unsigned int c[NCNT];
#pragma unroll
    for (int k = 0; k < NCNT; ++k) c[k] = 0u;

    const int T = blockDim.x;                      // 256
    // block-linear: each block owns a contiguous chunk (multiple of T*UNROLL)
    const int per_block = (n4 / gridDim.x) & ~(T * UNROLL - 1);
    const int base = blockIdx.x * per_block;

    for (int j = 0; j < per_block; j += T * UNROLL) {
        const int i = base + j + (int)threadIdx.x;
        v4f x0 = __builtin_nontemporal_load(&a[i]);
        v4f x1 = __builtin_nontemporal_load(&a[i + T]);
        v4f x2 = __builtin_nontemporal_load(&a[i + 2 * T]);
        v4f x3 = __builtin_nontemporal_load(&a[i + 3 * T]);
        v4f y0 = __builtin_nontemporal_load(&b[i]);
        v4f y1 = __builtin_nontemporal_load(&b[i + T]);
        v4f y2 = __builtin_nontemporal_load(&b[i + 2 * T]);
        v4f y3 = __builtin_nontemporal_load(&b[i + 3 * T]);
        // keep all 8 global_load_dwordx4 issued before any consumption
        __builtin_amdgcn_sched_barrier(0);
        count4(x0, y0, c);
        count4(x1, y1, c);
        count4(x2, y2, c);
        count4(x3, y3, c);
    }

    // remainder (empty for 512^3 with 2048 blocks; kept for generality)
    const int done = per_block * gridDim.x;
    for (int i = done + blockIdx.x * T + (int)threadIdx.x; i < n4;
         i += gridDim.x * T) {
        count4(a[i], b[i], c);
    }

    // wave-level reduction (wave = 64 lanes)
#pragma unroll
    for (int k = 0; k < NCNT; ++k) {
#pragma unroll
        for (int off = 32; off > 0; off >>= 1)
            c[k] += __shfl_down(c[k], off, 64);
    }

    __shared__ unsigned int s[4][NCNT];  // 256 threads -> 4 waves
    const int wave = threadIdx.x >> 6;
    const int lane = threadIdx.x & 63;
    if (lane == 0) {
#pragma unroll
        for (int k = 0; k < NCNT; ++k) s[wave][k] = c[k];
    }
    __syncthreads();
    if (threadIdx.x == 0) {
#pragma unroll
        for (int k = 0; k < NCNT; ++k) {
            unsigned int v = s[0][k] + s[1][k] + s[2][k] + s[3][k];
            atomicAdd(&counters[k], v);
        }
    }
}

__global__ void dice_finalize(const unsigned int* __restrict__ counters,
                              float* __restrict__ out) {
    const double eps = 1.1920928955078125e-07;  // np.float32 eps
    double acc = 0.0;
#pragma unroll
    for (int l = 0; l < 3; ++l) {
        double c1 = (double)counters[l];
        double c2 = (double)counters[3 + l];
        double in = (double)counters[6 + l];
        acc += (2.0 * in) / (c1 + c2 + eps);
    }
    out[0] = (float)(1.0 - acc / 3.0);
}

extern "C" void kernel_launch(void* const* d_in, const int* in_sizes, int n_in,
                              void* d_out, int out_size, void* d_ws, size_t ws_size,
                              hipStream_t stream) {
    const float* v1 = (const float*)d_in[0];
    const float* v2 = (const float*)d_in[1];
    float* out = (float*)d_out;
    unsigned int* counters = (unsigned int*)d_ws;

    const int n = in_sizes[0];        // 512^3 = 134217728, divisible by 4
    const int n4 = n >> 2;

    dice_zero_ws<<<1, 64, 0, stream>>>(counters);

    const int threads = 256;
    const int blocks = 2048;          // 8 blocks/CU -> 32 waves/CU; 256 KB
                                      // contiguous chunk per block per volume
    dice_count<<<blocks, threads, 0, stream>>>(
        (const v4f*)v1, (const v4f*)v2, counters, n4);

    dice_finalize<<<1, 1, 0, stream>>>(counters, out);
}